// Round 5
// baseline (430.880 us; speedup 1.0000x reference)
//
#include <hip/hip_runtime.h>
#include <stdint.h>

// ---------------------------------------------------------------------------
// MultiHeadAttention: out = softmax((qWq^T)(kWk^T)^T/sqrt(64)) (vWv^T) Wo^T
// B=4 S=2048 D=1024 H=16 dk=64.  All matmuls bf16 MFMA 16x16x32, fp32 acc.
// R5: attn K/V prefetch via VGPRs (loads issued after barrier-2, consumed by
//     ds_write after next barrier-1 -> global latency hidden under compute);
//     qkv GEMM converts fp32 activations in-kernel (cvt2 eliminated);
//     GEMMs back to (256,2); LDS addresses hoisted out of the kt loop.
// ---------------------------------------------------------------------------

typedef __attribute__((ext_vector_type(8))) short bf16x8;
typedef __attribute__((ext_vector_type(4))) float f32x4;

__device__ __forceinline__ void lds_async16(const void* g, void* l) {
  __builtin_amdgcn_global_load_lds(
      (const __attribute__((address_space(1))) void*)g,
      (__attribute__((address_space(3))) void*)l, 16, 0, 0);
}

__device__ __forceinline__ unsigned short f2bf(float f) {
  union { float f; unsigned u; } v; v.f = f;
  unsigned u = v.u + 0x7fffu + ((v.u >> 16) & 1u);   // RNE
  return (unsigned short)(u >> 16);
}

__device__ __forceinline__ float fast_exp2(float x) {
#if __has_builtin(__builtin_amdgcn_exp2f)
  return __builtin_amdgcn_exp2f(x);
#else
  return exp2f(x);
#endif
}

// pack 4 fp32 -> 4 bf16 (RNE) as uint2
__device__ __forceinline__ uint2 pack4(float a, float b, float c, float d) {
#if __has_builtin(__builtin_amdgcn_cvt_pk_bf16_f32)
  typedef __bf16 bf16v2 __attribute__((ext_vector_type(2)));
  union U { bf16v2 v; unsigned u; };
  U x, y;
  x.v = __builtin_amdgcn_cvt_pk_bf16_f32(a, b);
  y.v = __builtin_amdgcn_cvt_pk_bf16_f32(c, d);
  return make_uint2(x.u, y.u);
#else
  return make_uint2((unsigned)f2bf(a) | ((unsigned)f2bf(b) << 16),
                    (unsigned)f2bf(c) | ((unsigned)f2bf(d) << 16));
#endif
}

// two float4 -> 8 bf16 -> one 16B LDS store
__device__ __forceinline__ void cvt8_store(float4 a, float4 b, void* dst) {
  uint2 lo = pack4(a.x, a.y, a.z, a.w);
  uint2 hi = pack4(b.x, b.y, b.z, b.w);
  *(uint4*)dst = make_uint4(lo.x, lo.y, hi.x, hi.y);
}

// ---------------------------------------------------------------------------
// fp32 -> bf16 conversion (weights only now)
// ---------------------------------------------------------------------------
__global__ void cvt_kernel(const float* s0, const float* s1, const float* s2, const float* s3,
                           unsigned short* d0, unsigned short* d1, unsigned short* d2, unsigned short* d3,
                           int n4) {
  int which = blockIdx.y;
  const float* s = which == 0 ? s0 : which == 1 ? s1 : which == 2 ? s2 : s3;
  unsigned short* d = which == 0 ? d0 : which == 1 ? d1 : which == 2 ? d2 : d3;
  int i = blockIdx.x * 256 + threadIdx.x;
  if (i < n4) {
    float4 v = ((const float4*)s)[i];
    ushort4 o;
    o.x = f2bf(v.x); o.y = f2bf(v.y); o.z = f2bf(v.z); o.w = f2bf(v.w);
    ((ushort4*)d)[i] = o;
  }
}

// ---------------------------------------------------------------------------
// GEMM core: C[m][n] = sum_k A[m][k]*B[n][k], both row-major, K=1024.
// 128x128 tile, BK=64, XOR-swizzled LDS, 16x16x32 bf16 MFMA, 4x4/wave.
// AF/BF: that side is fp32 in global -> staged via VGPR prefetch + cvt +
// ds_write (pipelined: loads for k0+64 issued after barrier-2 of k0).
// bf16 sides use global_load_lds width 16.
// ---------------------------------------------------------------------------
struct GemmAcc { f32x4 acc[4][4]; };

template <bool AF, bool BF>
__device__ __forceinline__ void gemm_core2(const void* Ap, const void* Bp,
                                           int tm, int tn, unsigned short* As,
                                           unsigned short* Bs, GemmAcc& g) {
  constexpr int K = 1024;
  const int tid = threadIdx.x;
  const int lane = tid & 63;
  const int wv = tid >> 6;
  const int wm = wv & 1, wn = wv >> 1;
  const int c16 = lane & 15, q4 = lane >> 4;

#pragma unroll
  for (int i = 0; i < 4; ++i)
#pragma unroll
    for (int j = 0; j < 4; ++j)
#pragma unroll
      for (int r = 0; r < 4; ++r) g.acc[i][j][r] = 0.f;

  const int srow = tid >> 3;
  const int gc = (((tid & 7) ^ (srow & 7)) << 3);
  const unsigned short* Arow16 = (const unsigned short*)Ap + (size_t)(tm * 128 + srow) * K + gc;
  const unsigned short* Brow16 = (const unsigned short*)Bp + (size_t)(tn * 128 + srow) * K + gc;
  const float* Arow32 = (const float*)Ap + (size_t)(tm * 128 + srow) * K + gc;
  const float* Brow32 = (const float*)Bp + (size_t)(tn * 128 + srow) * K + gc;
  char* AsBase = (char*)As + tid * 16;
  char* BsBase = (char*)Bs + tid * 16;

  float4 pre[8];
  if (AF) {
#pragma unroll
    for (int i = 0; i < 4; ++i) {
      pre[2 * i]     = *(const float4*)(Arow32 + i * 32 * K);
      pre[2 * i + 1] = *(const float4*)(Arow32 + i * 32 * K + 4);
    }
  }
  if (BF) {
#pragma unroll
    for (int i = 0; i < 4; ++i) {
      pre[2 * i]     = *(const float4*)(Brow32 + i * 32 * K);
      pre[2 * i + 1] = *(const float4*)(Brow32 + i * 32 * K + 4);
    }
  }

  for (int k0 = 0; k0 < K; k0 += 64) {
    __syncthreads();
    if (AF) {
#pragma unroll
      for (int i = 0; i < 4; ++i) cvt8_store(pre[2 * i], pre[2 * i + 1], AsBase + i * 4096);
    } else {
#pragma unroll
      for (int i = 0; i < 4; ++i) lds_async16(Arow16 + k0 + i * 32 * K, AsBase + i * 4096);
    }
    if (BF) {
#pragma unroll
      for (int i = 0; i < 4; ++i) cvt8_store(pre[2 * i], pre[2 * i + 1], BsBase + i * 4096);
    } else {
#pragma unroll
      for (int i = 0; i < 4; ++i) lds_async16(Brow16 + k0 + i * 32 * K, BsBase + i * 4096);
    }
    __syncthreads();
    // prefetch next fp32 tile (issued AFTER the barrier so it isn't drained)
    if (AF && k0 + 64 < K) {
#pragma unroll
      for (int i = 0; i < 4; ++i) {
        pre[2 * i]     = *(const float4*)(Arow32 + k0 + 64 + i * 32 * K);
        pre[2 * i + 1] = *(const float4*)(Arow32 + k0 + 64 + i * 32 * K + 4);
      }
    }
    if (BF && k0 + 64 < K) {
#pragma unroll
      for (int i = 0; i < 4; ++i) {
        pre[2 * i]     = *(const float4*)(Brow32 + k0 + 64 + i * 32 * K);
        pre[2 * i + 1] = *(const float4*)(Brow32 + k0 + 64 + i * 32 * K + 4);
      }
    }
#pragma unroll
    for (int ks = 0; ks < 2; ++ks) {
      bf16x8 af[4], bfr[4];
#pragma unroll
      for (int i = 0; i < 4; ++i) {
        int mr = wm * 64 + i * 16 + c16;
        int pa = (ks * 4 + q4) ^ (mr & 7);
        af[i] = *(const bf16x8*)(As + mr * 64 + pa * 8);
        int nr = wn * 64 + i * 16 + c16;
        int pb = (ks * 4 + q4) ^ (nr & 7);
        bfr[i] = *(const bf16x8*)(Bs + nr * 64 + pb * 8);
      }
#pragma unroll
      for (int i = 0; i < 4; ++i)
#pragma unroll
        for (int j = 0; j < 4; ++j)
          g.acc[i][j] = __builtin_amdgcn_mfma_f32_16x16x32_bf16(af[i], bfr[j], g.acc[i][j], 0, 0, 0);
    }
  }
}

// ---------------------------------------------------------------------------
// Merged QKV projection (fp32 activations converted in-kernel).
// z=0: Q = q@Wq^T -> [bh][s][d] (scaled by 1/8*log2e); z=1: K likewise;
// z=2: V^T = Wv@v^T -> [bh][d][s] (fp32 side is B).
// ---------------------------------------------------------------------------
__global__ __launch_bounds__(256, 2)
void qkv_kernel(const float* __restrict__ qf, const float* __restrict__ kf,
                const float* __restrict__ vf,
                const unsigned short* __restrict__ wq, const unsigned short* __restrict__ wk,
                const unsigned short* __restrict__ wv_,
                unsigned short* __restrict__ Qb, unsigned short* __restrict__ Kb,
                unsigned short* __restrict__ Vtb) {
  __shared__ unsigned short As[128 * 64];
  __shared__ unsigned short Bs[128 * 64];
  const int z = blockIdx.z;
  int tm, tn;
  GemmAcc g;
  if (z == 0) {
    tm = blockIdx.y; tn = blockIdx.x;
    gemm_core2<true, false>(qf, wq, tm, tn, As, Bs, g);
  } else if (z == 1) {
    tm = blockIdx.y; tn = blockIdx.x;
    gemm_core2<true, false>(kf, wk, tm, tn, As, Bs, g);
  } else {
    tm = blockIdx.x; tn = blockIdx.y;
    gemm_core2<false, true>(wv_, vf, tm, tn, As, Bs, g);
  }

  const int lane = threadIdx.x & 63;
  const int wv = threadIdx.x >> 6;
  const int wm = wv & 1, wn = wv >> 1;
  const int c16 = lane & 15, q4 = lane >> 4;
  const float qscale = 0.125f * 1.44269504f;  // softmax scale * log2(e)

#pragma unroll
  for (int i = 0; i < 4; ++i)
#pragma unroll
    for (int j = 0; j < 4; ++j)
#pragma unroll
      for (int r = 0; r < 4; ++r) {
        int m = tm * 128 + wm * 64 + i * 16 + q4 * 4 + r;
        int n = tn * 128 + wn * 64 + j * 16 + c16;
        float val = g.acc[i][j][r];
        if (z < 2) {
          if (z == 0) val *= qscale;
          int b = m >> 11, s_ = m & 2047, h = n >> 6, d = n & 63;
          unsigned short* dst = z == 0 ? Qb : Kb;
          dst[(((size_t)(b * 16 + h) * 2048 + s_) << 6) | d] = f2bf(val);
        } else {
          int h = m >> 6, d = m & 63, b = n >> 11, s_ = n & 2047;
          Vtb[((size_t)((b * 16 + h) * 64 + d) << 11) | s_] = f2bf(val);
        }
      }
}

// ---------------------------------------------------------------------------
// Final projection: out = ctx @ Wo^T, fp32 row-major [8192,1024]
// ---------------------------------------------------------------------------
__global__ __launch_bounds__(256, 2)
void out_gemm(const unsigned short* __restrict__ A, const unsigned short* __restrict__ B,
              float* __restrict__ C) {
  __shared__ unsigned short As[128 * 64];
  __shared__ unsigned short Bs[128 * 64];
  GemmAcc g;
  gemm_core2<false, false>(A, B, blockIdx.y, blockIdx.x, As, Bs, g);
  const int lane = threadIdx.x & 63;
  const int wv = threadIdx.x >> 6;
  const int wm = wv & 1, wn = wv >> 1;
  const int c16 = lane & 15, q4 = lane >> 4;
#pragma unroll
  for (int i = 0; i < 4; ++i)
#pragma unroll
    for (int j = 0; j < 4; ++j)
#pragma unroll
      for (int r = 0; r < 4; ++r) {
        int m = blockIdx.y * 128 + wm * 64 + i * 16 + q4 * 4 + r;
        int n = blockIdx.x * 128 + wn * 64 + j * 16 + c16;
        C[(size_t)m * 1024 + n] = g.acc[i][j][r];
      }
}

// ---------------------------------------------------------------------------
// Flash attention, no-max softmax, K/V prefetched through VGPRs.
// Q,K: [bh][2048][64] (Q pre-scaled); Vt: [bh][64][2048].
// 1-D grid 1024, XCD-swizzled (xcd=idx&7 owns bh in [8*xcd, 8*xcd+8)).
// Block = 128 Q rows; wave w owns q-cols [w*32,w*32+32).  KV tile 128.
// S^T via mfma(kf,qf) -> packed b64 P-writes; l via ones-MFMA.
// LDS: Ks 16K + Vs 16K + Ps(stride 136) 34K = 66K -> 2 blocks/CU.
// ---------------------------------------------------------------------------
constexpr int PSS = 136;  // Ps row stride in shorts

__global__ __launch_bounds__(256, 2)
void attn_kernel(const unsigned short* __restrict__ Q,
                 const unsigned short* __restrict__ K,
                 const unsigned short* __restrict__ Vt,
                 unsigned short* __restrict__ ctx) {
  __shared__ unsigned short Ks[128 * 64];
  __shared__ unsigned short Vs[64 * 128];
  __shared__ unsigned short Ps[128 * PSS];

  const int tid = threadIdx.x, lane = tid & 63, w = tid >> 6;
  const int c16 = lane & 15, q4 = lane >> 4;
  const int wbase = w * 32;

  const int idx = blockIdx.x;
  const int slot = idx >> 3;
  const int bh = (idx & 7) * 8 + (slot >> 4);
  const int qt = slot & 15;

  const unsigned short* Qp = Q + ((size_t)bh * 2048 + qt * 128) * 64;
  const unsigned short* Kp = K + (size_t)bh * 2048 * 64;
  const unsigned short* Vp = Vt + (size_t)bh * 64 * 2048;

  const int srow8 = tid >> 3;
  const int gc8 = (((tid & 7) ^ (srow8 & 7)) << 3);

  // prefetch source pointers (per-thread, kt-invariant bases)
  const unsigned short* Kr = Kp + (size_t)srow8 * 64 + gc8;   // + kt*8192 + c*2048
  const int vrow = tid >> 4;
  const int vchunk = (tid & 15) ^ (vrow & 15);
  const unsigned short* Vr = Vp + (size_t)vrow * 2048 + vchunk * 8;  // + kt*128 + c*32768

  // ---- stage Q tile [128][64] into Ps (flat, stride 64) + prefetch tile 0 ----
  {
    const unsigned short* Qr = Qp + (size_t)srow8 * 64 + gc8;
    char* base = (char*)Ps + tid * 16;
#pragma unroll
    for (int c = 0; c < 4; ++c) lds_async16(Qr + c * 32 * 64, base + c * 4096);
  }
  uint4 kpre[4], vpre[4];
#pragma unroll
  for (int c = 0; c < 4; ++c) {
    kpre[c] = *(const uint4*)(Kr + c * 2048);
    vpre[c] = *(const uint4*)(Vr + c * 32768);
  }
  __syncthreads();

  bf16x8 qf[2][2];
#pragma unroll
  for (int nn = 0; nn < 2; ++nn)
#pragma unroll
    for (int ks = 0; ks < 2; ++ks) {
      int qr = wbase + nn * 16 + c16;
      int pos = (ks * 4 + q4) ^ (qr & 7);
      qf[nn][ks] = *(const bf16x8*)(Ps + qr * 64 + pos * 8);
    }

  bf16x8 onesf;
  {
    short v = (c16 == 0) ? (short)0x3F80 : (short)0;
#pragma unroll
    for (int j = 0; j < 8; ++j) onesf[j] = v;
  }

  f32x4 oacc[2][4];
  f32x4 lacc[2];
#pragma unroll
  for (int mm = 0; mm < 2; ++mm) {
#pragma unroll
    for (int r = 0; r < 4; ++r) lacc[mm][r] = 0.f;
#pragma unroll
    for (int dj = 0; dj < 4; ++dj)
#pragma unroll
      for (int r = 0; r < 4; ++r) oacc[mm][dj][r] = 0.f;
  }

  // ---- hoisted LDS pointers (all pos-xors are kt-invariant) ----
  const unsigned short* kb0 = Ks + c16 * 64 + ((q4 ^ (c16 & 7)) * 8);
  const unsigned short* kb1 = Ks + c16 * 64 + (((4 + q4) ^ (c16 & 7)) * 8);
  const unsigned short* vb_[4];
#pragma unroll
  for (int ks2 = 0; ks2 < 4; ++ks2)
    vb_[ks2] = Vs + c16 * 128 + (((ks2 * 4 + q4) ^ c16) * 8);
  const unsigned short* pb[4];
#pragma unroll
  for (int ks2 = 0; ks2 < 4; ++ks2)
    pb[ks2] = Ps + (wbase + c16) * PSS + (ks2 * 4 + q4) * 8;
  unsigned short* pw0 = Ps + (wbase + c16) * PSS + (q4 >> 1) * 8 + (q4 & 1) * 4;
  unsigned short* pw1 = pw0 + 16 * PSS;

  for (int kt = 0; kt < 16; ++kt) {
    __syncthreads();  // (1) prior tile's LDS reads done
    // ---- ds_write staged K/V tile from prefetch regs ----
#pragma unroll
    for (int c = 0; c < 4; ++c) {
      *(uint4*)((char*)Ks + tid * 16 + c * 4096) = kpre[c];
      *(uint4*)((char*)Vs + tid * 16 + c * 4096) = vpre[c];
    }
    __syncthreads();  // (2) LDS writes visible
    // ---- prefetch tile kt+1 (clamped; issued after barrier -> never drained early)
    {
      int ktn = (kt < 15) ? kt + 1 : 15;
#pragma unroll
      for (int c = 0; c < 4; ++c) {
        kpre[c] = *(const uint4*)(Kr + (size_t)ktn * 8192 + c * 2048);
        vpre[c] = *(const uint4*)(Vr + (size_t)ktn * 128 + c * 32768);
      }
    }

    // ---- S^T = K Q^T; exp2; packed P-writes ----
#pragma unroll
    for (int m = 0; m < 8; ++m) {
      bf16x8 kf0 = *(const bf16x8*)(kb0 + m * 1024);
      bf16x8 kf1 = *(const bf16x8*)(kb1 + m * 1024);
      f32x4 s0 = {0.f, 0.f, 0.f, 0.f}, s1 = {0.f, 0.f, 0.f, 0.f};
      s0 = __builtin_amdgcn_mfma_f32_16x16x32_bf16(kf0, qf[0][0], s0, 0, 0, 0);
      s0 = __builtin_amdgcn_mfma_f32_16x16x32_bf16(kf1, qf[0][1], s0, 0, 0, 0);
      s1 = __builtin_amdgcn_mfma_f32_16x16x32_bf16(kf0, qf[1][0], s1, 0, 0, 0);
      s1 = __builtin_amdgcn_mfma_f32_16x16x32_bf16(kf1, qf[1][1], s1, 0, 0, 0);
      *(uint2*)(pw0 + m * 16) =
          pack4(fast_exp2(s0[0]), fast_exp2(s0[1]), fast_exp2(s0[2]), fast_exp2(s0[3]));
      *(uint2*)(pw1 + m * 16) =
          pack4(fast_exp2(s1[0]), fast_exp2(s1[1]), fast_exp2(s1[2]), fast_exp2(s1[3]));
    }

    // ---- O += P V, l += P 1 (P rows wave-private -> no barrier) ----
#pragma unroll
    for (int ks2 = 0; ks2 < 4; ++ks2) {
      bf16x8 vfr[4];
#pragma unroll
      for (int dj = 0; dj < 4; ++dj) vfr[dj] = *(const bf16x8*)(vb_[ks2] + dj * 2048);
      bf16x8 pf0 = *(const bf16x8*)(pb[ks2]);
      bf16x8 pf1 = *(const bf16x8*)(pb[ks2] + 16 * PSS);
      lacc[0] = __builtin_amdgcn_mfma_f32_16x16x32_bf16(pf0, onesf, lacc[0], 0, 0, 0);
      lacc[1] = __builtin_amdgcn_mfma_f32_16x16x32_bf16(pf1, onesf, lacc[1], 0, 0, 0);
#pragma unroll
      for (int dj = 0; dj < 4; ++dj) {
        oacc[0][dj] = __builtin_amdgcn_mfma_f32_16x16x32_bf16(pf0, vfr[dj], oacc[0][dj], 0, 0, 0);
        oacc[1][dj] = __builtin_amdgcn_mfma_f32_16x16x32_bf16(pf1, vfr[dj], oacc[1][dj], 0, 0, 0);
      }
    }
  }

  // ---- epilogue: l broadcast, normalize, write ctx [B, S, 1024] bf16 ----
  int b = bh >> 4, h = bh & 15;
#pragma unroll
  for (int mm = 0; mm < 2; ++mm)
#pragma unroll
    for (int r = 0; r < 4; ++r) {
      float l = __shfl(lacc[mm][r], lane & 48, 64);
      float inv = 1.f / l;
      int s_ = qt * 128 + wbase + mm * 16 + q4 * 4 + r;
#pragma unroll
      for (int dj = 0; dj < 4; ++dj) {
        int d = dj * 16 + c16;
        ctx[((size_t)(b * 2048 + s_)) * 1024 + h * 64 + d] = f2bf(oacc[mm][dj][r] * inv);
      }
    }
}

// ---------------------------------------------------------------------------
extern "C" void kernel_launch(void* const* d_in, const int* in_sizes, int n_in,
                              void* d_out, int out_size, void* d_ws, size_t ws_size,
                              hipStream_t stream) {
  const float* q  = (const float*)d_in[0];
  const float* k  = (const float*)d_in[1];
  const float* v  = (const float*)d_in[2];
  const float* Wq = (const float*)d_in[3];
  const float* Wk = (const float*)d_in[4];
  const float* Wv = (const float*)d_in[5];
  const float* Wo = (const float*)d_in[6];

  char* ws = (char*)d_ws;
  unsigned short* ctxb = (unsigned short*)(ws);                  // 16 MB
  unsigned short* wqb  = (unsigned short*)(ws + (48u << 20));
  unsigned short* wkb  = (unsigned short*)(ws + (50u << 20));
  unsigned short* wvb  = (unsigned short*)(ws + (52u << 20));
  unsigned short* wob  = (unsigned short*)(ws + (54u << 20));
  unsigned short* Qb   = (unsigned short*)(ws + (56u << 20));
  unsigned short* Kb   = (unsigned short*)(ws + (72u << 20));
  unsigned short* Vtb  = (unsigned short*)(ws + (88u << 20));

  cvt_kernel<<<dim3(1024, 4), 256, 0, stream>>>(Wq, Wk, Wv, Wo, wqb, wkb, wvb, wob, 262144);

  qkv_kernel<<<dim3(8, 64, 3), 256, 0, stream>>>(q, k, v, wqb, wkb, wvb, Qb, Kb, Vtb);

  attn_kernel<<<dim3(1024), 256, 0, stream>>>(Qb, Kb, Vtb, ctxb);

  out_gemm<<<dim3(8, 64), 256, 0, stream>>>(ctxb, wob, (float*)d_out);
}

// Round 6
// 343.751 us; speedup vs baseline: 1.2535x; 1.2535x over previous
//
#include <hip/hip_runtime.h>
#include <stdint.h>

// ---------------------------------------------------------------------------
// MultiHeadAttention: out = softmax((qWq^T)(kWk^T)^T/sqrt(64)) (vWv^T) Wo^T
// B=4 S=2048 D=1024 H=16 dk=64.  All matmuls bf16 MFMA 16x16x32, fp32 acc.
// R6: attn = single-barrier K/V LDS double-buffer (global_load_lds issued
//     after the barrier, drained one full compute phase later), KV-tile 64,
//     50 KB LDS -> 3 blocks/CU.  R5's VGPR prefetch (scratch spill, 310 MB
//     WRITE_SIZE) reverted; qkv/out_gemm back to bf16 global_load_lds form.
// ---------------------------------------------------------------------------

typedef __attribute__((ext_vector_type(8))) short bf16x8;
typedef __attribute__((ext_vector_type(4))) float f32x4;

__device__ __forceinline__ void lds_async16(const void* g, void* l) {
  __builtin_amdgcn_global_load_lds(
      (const __attribute__((address_space(1))) void*)g,
      (__attribute__((address_space(3))) void*)l, 16, 0, 0);
}

__device__ __forceinline__ unsigned short f2bf(float f) {
  union { float f; unsigned u; } v; v.f = f;
  unsigned u = v.u + 0x7fffu + ((v.u >> 16) & 1u);   // RNE
  return (unsigned short)(u >> 16);
}

__device__ __forceinline__ float fast_exp2(float x) {
#if __has_builtin(__builtin_amdgcn_exp2f)
  return __builtin_amdgcn_exp2f(x);
#else
  return exp2f(x);
#endif
}

// pack 4 fp32 -> 4 bf16 (RNE) as uint2
__device__ __forceinline__ uint2 pack4(float a, float b, float c, float d) {
#if __has_builtin(__builtin_amdgcn_cvt_pk_bf16_f32)
  typedef __bf16 bf16v2 __attribute__((ext_vector_type(2)));
  union U { bf16v2 v; unsigned u; };
  U x, y;
  x.v = __builtin_amdgcn_cvt_pk_bf16_f32(a, b);
  y.v = __builtin_amdgcn_cvt_pk_bf16_f32(c, d);
  return make_uint2(x.u, y.u);
#else
  return make_uint2((unsigned)f2bf(a) | ((unsigned)f2bf(b) << 16),
                    (unsigned)f2bf(c) | ((unsigned)f2bf(d) << 16));
#endif
}

// ---------------------------------------------------------------------------
// fp32 -> bf16 conversion, 4 els/thread, buffer selected by blockIdx.y
// ---------------------------------------------------------------------------
__global__ void cvt_kernel(const float* s0, const float* s1, const float* s2, const float* s3,
                           unsigned short* d0, unsigned short* d1, unsigned short* d2, unsigned short* d3,
                           int n4) {
  int which = blockIdx.y;
  const float* s = which == 0 ? s0 : which == 1 ? s1 : which == 2 ? s2 : s3;
  unsigned short* d = which == 0 ? d0 : which == 1 ? d1 : which == 2 ? d2 : d3;
  int i = blockIdx.x * 256 + threadIdx.x;
  if (i < n4) {
    float4 v = ((const float4*)s)[i];
    ushort4 o;
    o.x = f2bf(v.x); o.y = f2bf(v.y); o.z = f2bf(v.z); o.w = f2bf(v.w);
    ((ushort4*)d)[i] = o;
  }
}

// ---------------------------------------------------------------------------
// GEMM core: C[m][n] = sum_k A[m][k]*B[n][k], both bf16 row-major, K=1024.
// 128x128 tile, BK=64, XOR-swizzled LDS, 16x16x32 bf16 MFMA, 4x4/wave.
// ---------------------------------------------------------------------------
struct GemmAcc { f32x4 acc[4][4]; };

__device__ __forceinline__ void gemm_core(const unsigned short* __restrict__ Arows,
                                          const unsigned short* __restrict__ Brows,
                                          int tm, int tn, unsigned short* As,
                                          unsigned short* Bs, GemmAcc& g) {
  constexpr int K = 1024;
  const int tid = threadIdx.x;
  const int lane = tid & 63;
  const int wv = tid >> 6;
  const int wm = wv & 1, wn = wv >> 1;
  const int c16 = lane & 15, q4 = lane >> 4;

#pragma unroll
  for (int i = 0; i < 4; ++i)
#pragma unroll
    for (int j = 0; j < 4; ++j)
#pragma unroll
      for (int r = 0; r < 4; ++r) g.acc[i][j][r] = 0.f;

  const int srow = tid >> 3;
  const int gc = (((tid & 7) ^ (srow & 7)) << 3);
  const unsigned short* Arow = Arows + (size_t)(tm * 128 + srow) * K + gc;
  const unsigned short* Brow = Brows + (size_t)(tn * 128 + srow) * K + gc;
  char* AsBase = (char*)As + tid * 16;
  char* BsBase = (char*)Bs + tid * 16;

  for (int k0 = 0; k0 < K; k0 += 64) {
    __syncthreads();
#pragma unroll
    for (int i = 0; i < 4; ++i) {
      lds_async16(Arow + k0 + i * 32 * K, AsBase + i * 4096);
      lds_async16(Brow + k0 + i * 32 * K, BsBase + i * 4096);
    }
    __syncthreads();
#pragma unroll
    for (int ks = 0; ks < 2; ++ks) {
      bf16x8 af[4], bfr[4];
#pragma unroll
      for (int i = 0; i < 4; ++i) {
        int mr = wm * 64 + i * 16 + c16;
        int pa = (ks * 4 + q4) ^ (mr & 7);
        af[i] = *(const bf16x8*)(As + mr * 64 + pa * 8);
        int nr = wn * 64 + i * 16 + c16;
        int pb = (ks * 4 + q4) ^ (nr & 7);
        bfr[i] = *(const bf16x8*)(Bs + nr * 64 + pb * 8);
      }
#pragma unroll
      for (int i = 0; i < 4; ++i)
#pragma unroll
        for (int j = 0; j < 4; ++j)
          g.acc[i][j] = __builtin_amdgcn_mfma_f32_16x16x32_bf16(af[i], bfr[j], g.acc[i][j], 0, 0, 0);
    }
  }
}

// ---------------------------------------------------------------------------
// Merged QKV projection.  z=0: Q = q@Wq^T -> [bh][s][d] (scaled by 1/8*log2e);
// z=1: K -> [bh][s][d];  z=2: V^T = Wv@v^T -> [bh][d][s].
// ---------------------------------------------------------------------------
__global__ __launch_bounds__(256, 2)
void qkv_kernel(const unsigned short* __restrict__ qb, const unsigned short* __restrict__ kb,
                const unsigned short* __restrict__ vb,
                const unsigned short* __restrict__ wq, const unsigned short* __restrict__ wk,
                const unsigned short* __restrict__ wv_,
                unsigned short* __restrict__ Qb, unsigned short* __restrict__ Kb,
                unsigned short* __restrict__ Vtb) {
  __shared__ unsigned short As[128 * 64];
  __shared__ unsigned short Bs[128 * 64];
  const int z = blockIdx.z;
  const unsigned short* A;
  const unsigned short* B;
  int tm, tn;
  if (z == 0)      { A = qb;  B = wq;  tm = blockIdx.y; tn = blockIdx.x; }
  else if (z == 1) { A = kb;  B = wk;  tm = blockIdx.y; tn = blockIdx.x; }
  else             { A = wv_; B = vb;  tm = blockIdx.x; tn = blockIdx.y; }

  GemmAcc g;
  gemm_core(A, B, tm, tn, As, Bs, g);

  const int lane = threadIdx.x & 63;
  const int wv = threadIdx.x >> 6;
  const int wm = wv & 1, wn = wv >> 1;
  const int c16 = lane & 15, q4 = lane >> 4;
  const float qscale = 0.125f * 1.44269504f;  // softmax scale * log2(e)

#pragma unroll
  for (int i = 0; i < 4; ++i)
#pragma unroll
    for (int j = 0; j < 4; ++j)
#pragma unroll
      for (int r = 0; r < 4; ++r) {
        int m = tm * 128 + wm * 64 + i * 16 + q4 * 4 + r;
        int n = tn * 128 + wn * 64 + j * 16 + c16;
        float val = g.acc[i][j][r];
        if (z < 2) {
          if (z == 0) val *= qscale;
          int b = m >> 11, s_ = m & 2047, h = n >> 6, d = n & 63;
          unsigned short* dst = z == 0 ? Qb : Kb;
          dst[(((size_t)(b * 16 + h) * 2048 + s_) << 6) | d] = f2bf(val);
        } else {
          int h = m >> 6, d = m & 63, b = n >> 11, s_ = n & 2047;
          Vtb[((size_t)((b * 16 + h) * 64 + d) << 11) | s_] = f2bf(val);
        }
      }
}

// ---------------------------------------------------------------------------
// Final projection: out = ctx @ Wo^T, fp32 row-major [8192,1024]
// ---------------------------------------------------------------------------
__global__ __launch_bounds__(256, 2)
void out_gemm(const unsigned short* __restrict__ A, const unsigned short* __restrict__ B,
              float* __restrict__ C) {
  __shared__ unsigned short As[128 * 64];
  __shared__ unsigned short Bs[128 * 64];
  GemmAcc g;
  gemm_core(A, B, blockIdx.y, blockIdx.x, As, Bs, g);
  const int lane = threadIdx.x & 63;
  const int wv = threadIdx.x >> 6;
  const int wm = wv & 1, wn = wv >> 1;
  const int c16 = lane & 15, q4 = lane >> 4;
#pragma unroll
  for (int i = 0; i < 4; ++i)
#pragma unroll
    for (int j = 0; j < 4; ++j)
#pragma unroll
      for (int r = 0; r < 4; ++r) {
        int m = blockIdx.y * 128 + wm * 64 + i * 16 + q4 * 4 + r;
        int n = blockIdx.x * 128 + wn * 64 + j * 16 + c16;
        C[(size_t)m * 1024 + n] = g.acc[i][j][r];
      }
}

// ---------------------------------------------------------------------------
// Flash attention, no-max softmax, LDS double-buffered K/V (tile 64).
// Q,K: [bh][2048][64] (Q pre-scaled); Vt: [bh][64][2048].
// 1-D grid 1024, XCD-swizzled (xcd=idx&7 owns bh in [8*xcd, 8*xcd+8)).
// Block = 128 Q rows; wave w owns q-cols [w*32,w*32+32).
// Per iter: issue DMA for tile kt+1 into alt buffer, compute tile kt, one
// barrier (vmcnt drain lands a full compute phase after issue).
// LDS: Ks 2x8K + Vs 2x8K + Ps 128x72x2B = 50 KB -> 3 blocks/CU.
// ---------------------------------------------------------------------------
constexpr int PSS = 72;  // Ps row stride in shorts (bank rotation by 4/row)

__global__ __launch_bounds__(256, 3)
void attn_kernel(const unsigned short* __restrict__ Q,
                 const unsigned short* __restrict__ K,
                 const unsigned short* __restrict__ Vt,
                 unsigned short* __restrict__ ctx) {
  __shared__ unsigned short Ks[2][64 * 64];  // K tile [k][d], chunk^(k&7)
  __shared__ unsigned short Vs[2][64 * 64];  // V^T tile [d][k], chunk^(d&7)
  __shared__ unsigned short Ps[128 * PSS];   // P [q][k-tile]; Q staged here first (flat [128][64])

  const int tid = threadIdx.x, lane = tid & 63, w = tid >> 6;
  const int c16 = lane & 15, q4 = lane >> 4;
  const int wbase = w * 32;

  // XCD-aware swizzle: idx&7 = XCD; each XCD owns 8 consecutive bh.
  const int idx = blockIdx.x;
  const int slot = idx >> 3;
  const int bh = (idx & 7) * 8 + (slot >> 4);
  const int qt = slot & 15;

  const unsigned short* Qp = Q + ((size_t)bh * 2048 + qt * 128) * 64;
  const unsigned short* Kp = K + (size_t)bh * 2048 * 64;
  const unsigned short* Vp = Vt + (size_t)bh * 64 * 2048;

  const int srow8 = tid >> 3;                        // 0..31
  const int gc8 = (((tid & 7) ^ (srow8 & 7)) << 3);  // swizzled 8-short chunk offset

  // staging sources (row r = srow8 + 32c)
  const unsigned short* Krs = Kp + (size_t)srow8 * 64 + gc8;           // + kt*4096 + c*2048
  const unsigned short* Vrs = Vp + (size_t)srow8 * 2048 + gc8;         // + kt*64 + c*65536
  char* KdBase = (char*)&Ks[0][0] + tid * 16;                          // + nb*8192 + c*4096
  char* VdBase = (char*)&Vs[0][0] + tid * 16;

  // ---- prologue: stage Q tile [128][64] into Ps (flat) + K/V tile 0 ----
  {
    const unsigned short* Qr = Qp + (size_t)srow8 * 64 + gc8;
    char* base = (char*)Ps + tid * 16;
#pragma unroll
    for (int c = 0; c < 4; ++c) lds_async16(Qr + c * 32 * 64, base + c * 4096);
  }
#pragma unroll
  for (int c = 0; c < 2; ++c) {
    lds_async16(Krs + c * 2048, KdBase + c * 4096);
    lds_async16(Vrs + c * 65536, VdBase + c * 4096);
  }
  __syncthreads();

  bf16x8 qf[2][2];
#pragma unroll
  for (int nn = 0; nn < 2; ++nn)
#pragma unroll
    for (int ks = 0; ks < 2; ++ks) {
      int qr = wbase + nn * 16 + c16;
      int pos = (ks * 4 + q4) ^ (qr & 7);
      qf[nn][ks] = *(const bf16x8*)(Ps + qr * 64 + pos * 8);
    }
  __syncthreads();  // all qf reads done before any wave's P-writes reuse Ps

  bf16x8 onesf;
  {
    short v = (c16 == 0) ? (short)0x3F80 : (short)0;
#pragma unroll
    for (int j = 0; j < 8; ++j) onesf[j] = v;
  }

  f32x4 oacc[2][4];
  f32x4 lacc[2];
#pragma unroll
  for (int mm = 0; mm < 2; ++mm) {
#pragma unroll
    for (int r = 0; r < 4; ++r) lacc[mm][r] = 0.f;
#pragma unroll
    for (int dj = 0; dj < 4; ++dj)
#pragma unroll
      for (int r = 0; r < 4; ++r) oacc[mm][dj][r] = 0.f;
  }

  // hoisted LDS offsets (element units, buffer-relative)
  const int kb0 = c16 * 64 + ((q4 ^ (c16 & 7)) * 8);
  const int kb1 = c16 * 64 + (((4 + q4) ^ (c16 & 7)) * 8);
  int vbo[2];
#pragma unroll
  for (int ks2 = 0; ks2 < 2; ++ks2)
    vbo[ks2] = c16 * 64 + (((ks2 * 4 + q4) ^ (c16 & 7)) * 8);
  const unsigned short* pb0 = Ps + (wbase + c16) * PSS + q4 * 8;  // + ks2*32
  unsigned short* pw0 = Ps + (wbase + c16) * PSS + q4 * 4;        // + m*16
  unsigned short* pw1 = pw0 + 16 * PSS;

  for (int kt = 0; kt < 32; ++kt) {
    const unsigned short* KsC = &Ks[kt & 1][0];
    const unsigned short* VsC = &Vs[kt & 1][0];
    // ---- issue DMA for tile kt+1 into alt buffer (drained at loop-end barrier)
    if (kt < 31) {
      int nb = (kt + 1) & 1;
      size_t ko = (size_t)(kt + 1) * 4096;  // K advance: 64 rows * 64
      size_t vo = (size_t)(kt + 1) * 64;    // V advance: 64 cols
#pragma unroll
      for (int c = 0; c < 2; ++c) {
        lds_async16(Krs + ko + c * 2048, KdBase + nb * 8192 + c * 4096);
        lds_async16(Vrs + vo + c * 65536, VdBase + nb * 8192 + c * 4096);
      }
    }

    // ---- S^T = K Q^T (4 k-subtiles); exp2; packed P-writes ----
#pragma unroll
    for (int m = 0; m < 4; ++m) {
      bf16x8 kf0 = *(const bf16x8*)(KsC + kb0 + m * 1024);
      bf16x8 kf1 = *(const bf16x8*)(KsC + kb1 + m * 1024);
      f32x4 s0 = {0.f, 0.f, 0.f, 0.f}, s1 = {0.f, 0.f, 0.f, 0.f};
      s0 = __builtin_amdgcn_mfma_f32_16x16x32_bf16(kf0, qf[0][0], s0, 0, 0, 0);
      s0 = __builtin_amdgcn_mfma_f32_16x16x32_bf16(kf1, qf[0][1], s0, 0, 0, 0);
      s1 = __builtin_amdgcn_mfma_f32_16x16x32_bf16(kf0, qf[1][0], s1, 0, 0, 0);
      s1 = __builtin_amdgcn_mfma_f32_16x16x32_bf16(kf1, qf[1][1], s1, 0, 0, 0);
      *(uint2*)(pw0 + m * 16) =
          pack4(fast_exp2(s0[0]), fast_exp2(s0[1]), fast_exp2(s0[2]), fast_exp2(s0[3]));
      *(uint2*)(pw1 + m * 16) =
          pack4(fast_exp2(s1[0]), fast_exp2(s1[1]), fast_exp2(s1[2]), fast_exp2(s1[3]));
    }

    // ---- O += P V, l += P 1 (P rows wave-private -> no barrier) ----
#pragma unroll
    for (int ks2 = 0; ks2 < 2; ++ks2) {
      bf16x8 vfr[4];
#pragma unroll
      for (int dj = 0; dj < 4; ++dj) vfr[dj] = *(const bf16x8*)(VsC + vbo[ks2] + dj * 1024);
      bf16x8 pf0 = *(const bf16x8*)(pb0 + ks2 * 32);
      bf16x8 pf1 = *(const bf16x8*)(pb0 + ks2 * 32 + 16 * PSS);
      lacc[0] = __builtin_amdgcn_mfma_f32_16x16x32_bf16(pf0, onesf, lacc[0], 0, 0, 0);
      lacc[1] = __builtin_amdgcn_mfma_f32_16x16x32_bf16(pf1, onesf, lacc[1], 0, 0, 0);
#pragma unroll
      for (int dj = 0; dj < 4; ++dj) {
        oacc[0][dj] = __builtin_amdgcn_mfma_f32_16x16x32_bf16(pf0, vfr[dj], oacc[0][dj], 0, 0, 0);
        oacc[1][dj] = __builtin_amdgcn_mfma_f32_16x16x32_bf16(pf1, vfr[dj], oacc[1][dj], 0, 0, 0);
      }
    }

    __syncthreads();  // reads of buf[kt&1] done + DMA for kt+1 drained
  }

  // ---- epilogue: l broadcast (col0 at lane q4*16), normalize, store ----
  int b = bh >> 4, h = bh & 15;
#pragma unroll
  for (int mm = 0; mm < 2; ++mm)
#pragma unroll
    for (int r = 0; r < 4; ++r) {
      float l = __shfl(lacc[mm][r], lane & 48, 64);
      float inv = 1.f / l;
      int s_ = qt * 128 + wbase + mm * 16 + q4 * 4 + r;
#pragma unroll
      for (int dj = 0; dj < 4; ++dj) {
        int d = dj * 16 + c16;
        ctx[((size_t)(b * 2048 + s_)) * 1024 + h * 64 + d] = f2bf(oacc[mm][dj][r] * inv);
      }
    }
}

// ---------------------------------------------------------------------------
extern "C" void kernel_launch(void* const* d_in, const int* in_sizes, int n_in,
                              void* d_out, int out_size, void* d_ws, size_t ws_size,
                              hipStream_t stream) {
  const float* q  = (const float*)d_in[0];
  const float* k  = (const float*)d_in[1];
  const float* v  = (const float*)d_in[2];
  const float* Wq = (const float*)d_in[3];
  const float* Wk = (const float*)d_in[4];
  const float* Wv = (const float*)d_in[5];
  const float* Wo = (const float*)d_in[6];

  char* ws = (char*)d_ws;
  unsigned short* qb  = (unsigned short*)(ws);                    // 16 MB (reused as ctx)
  unsigned short* kb  = (unsigned short*)(ws + (16u << 20));
  unsigned short* vb  = (unsigned short*)(ws + (32u << 20));
  unsigned short* wqb = (unsigned short*)(ws + (48u << 20));
  unsigned short* wkb = (unsigned short*)(ws + (50u << 20));
  unsigned short* wvb = (unsigned short*)(ws + (52u << 20));
  unsigned short* wob = (unsigned short*)(ws + (54u << 20));
  unsigned short* Qb  = (unsigned short*)(ws + (56u << 20));
  unsigned short* Kb  = (unsigned short*)(ws + (72u << 20));
  unsigned short* Vtb = (unsigned short*)(ws + (88u << 20));
  unsigned short* ctxb = qb;  // q-bf16 dead after projections

  cvt_kernel<<<dim3(1024, 4), 256, 0, stream>>>(Wq, Wk, Wv, Wo, wqb, wkb, wvb, wob, 262144);
  cvt_kernel<<<dim3(8192, 3), 256, 0, stream>>>(q, k, v, q, qb, kb, vb, qb, 2097152);

  qkv_kernel<<<dim3(8, 64, 3), 256, 0, stream>>>(qb, kb, vb, wqb, wkb, wvb, Qb, Kb, Vtb);

  attn_kernel<<<dim3(1024), 256, 0, stream>>>(Qb, Kb, Vtb, ctxb);

  out_gemm<<<dim3(8, 64), 256, 0, stream>>>(ctxb, wob, (float*)d_out);
}